// Round 1
// baseline (126.160 us; speedup 1.0000x reference)
//
#include <hip/hip_runtime.h>

#define HDIM 768
#define EDIM 128
#define BDIM 64

// Grid: 256 core blocks (each reduces 4 of the 8 chunks of one core[i,:,:])
//     + 768 proj blocks (unchanged math from the verified kernel).
// The LAST block to finish (atomic ticket) performs the final combine that
// used to be final_kernel — bit-identical arithmetic, one dispatch total.
#define NCORE_BLOCKS 256
#define NPROJ_BLOCKS 768
#define NBLOCKS (NCORE_BLOCKS + NPROJ_BLOCKS)

__device__ unsigned int g_count = 0;  // zero-init at module load; restored to 0 each run

__global__ __launch_bounds__(256) void fused_all(
    const float* __restrict__ core,
    const float* __restrict__ head_src, const float* __restrict__ rel_src,
    const float* __restrict__ tail_src,
    const float* __restrict__ W_e, const float* __restrict__ b_e,
    const float* __restrict__ W_r, const float* __restrict__ b_r,
    float* __restrict__ partials, float* __restrict__ P,
    float* __restrict__ out) {
  __shared__ float wpart[4][4];   // [chunk u][wave]
  __shared__ float s_S[EDIM];
  __shared__ int s_last;
  const int blk = blockIdx.x;
  const int t = threadIdx.x;
  const int wave = t >> 6, lane = t & 63;

  if (blk < NCORE_BLOCKS) {
    // core[i, :, :] reduction: block handles chunks half*4 .. half*4+3 of i.
    const int i = blk >> 1;
    const int half = blk & 1;
    const float* base = core + (size_t)i * (EDIM * EDIM) + (size_t)half * 8192;
    float s[4];
#pragma unroll
    for (int u = 0; u < 4; ++u) {
      const float4* p = (const float4*)(base + u * 2048);
      const float4 a = p[t];
      const float4 b = p[t + 256];
      s[u] = (a.x + a.y) + (a.z + a.w) + (b.x + b.y) + (b.z + b.w);
    }
#pragma unroll
    for (int off = 32; off; off >>= 1) {
#pragma unroll
      for (int u = 0; u < 4; ++u) s[u] += __shfl_down(s[u], off, 64);
    }
    if (lane == 0) {
#pragma unroll
      for (int u = 0; u < 4; ++u) wpart[u][wave] = s[u];
    }
    __syncthreads();
    if (t < 4)
      partials[i * 8 + half * 4 + t] =
          (wpart[t][0] + wpart[t][1]) + (wpart[t][2] + wpart[t][3]);
  } else {
    // Projections: identical math to the verified kernel.
    const int pid = blk - NCORE_BLOCKS;
    const int wg = pid * 4 + wave;      // 0..3071
    const int ich = wg & 15;            // i-chunk 0..15
    const int mb = wg >> 4;             // 0..191
    const int m = mb >> 6;              // 0=head 1=rel 2=tail
    const int b = mb & 63;

    const float* src  = (m == 0) ? head_src : (m == 1) ? rel_src : tail_src;
    const float* W    = (m == 1) ? W_r : W_e;
    const float* bias = (m == 1) ? b_r : b_e;

    const float4* s4 = (const float4*)(src + b * HDIM);
    const float4 x0 = s4[lane], x1 = s4[lane + 64], x2 = s4[lane + 128];

    const int i0 = ich * 8;
#pragma unroll
    for (int u = 0; u < 8; ++u) {
      const int i = i0 + u;
      const float4* w4 = (const float4*)(W + i * HDIM);
      const float4 w0 = w4[lane], w1 = w4[lane + 64], w2 = w4[lane + 128];
      float d = w0.x * x0.x + w0.y * x0.y + w0.z * x0.z + w0.w * x0.w
              + w1.x * x1.x + w1.y * x1.y + w1.z * x1.z + w1.w * x1.w
              + w2.x * x2.x + w2.y * x2.y + w2.z * x2.z + w2.w * x2.w;
#pragma unroll
      for (int off = 32; off; off >>= 1) d += __shfl_down(d, off, 64);
      if (lane == 0) P[(m * BDIM + b) * EDIM + i] = d + bias[i];
    }
  }

  // ---- last-block-done epilogue (replaces final_kernel) ----
  // Release: push this block's global stores to a device-visible point
  // (L2 writeback only — avoid __threadfence()'s buffer_inv, which would
  // repeatedly evict the shared W tiles from each XCD's L2).
  __builtin_amdgcn_fence(__ATOMIC_RELEASE, "agent");
  __syncthreads();
  if (t == 0) {
    const unsigned int old = atomicAdd(&g_count, 1u);
    s_last = (old == (unsigned int)(NBLOCKS - 1));
  }
  __syncthreads();
  if (!s_last) return;
  __builtin_amdgcn_fence(__ATOMIC_ACQUIRE, "agent");  // see all other blocks' stores

  // S[i] = sum of 8 chunk partials, same order as old final_kernel.
  if (t < EDIM) {
    float S = 0.f;
#pragma unroll
    for (int c = 0; c < 8; ++c) S += partials[t * 8 + c];
    s_S[t] = S;
  }
  __syncthreads();

  // Wave w handles b = w*16 .. w*16+15. Lane l covers i=l (low, == old wave0
  // of final_kernel) and i=l+64 (high, == old wave1); the two shuffle trees
  // and the final (low+high) combine replicate the old arithmetic exactly.
#pragma unroll 2
  for (int bb = 0; bb < 16; ++bb) {
    const int b = wave * 16 + bb;
    const float hL = P[(0 * BDIM + b) * EDIM + lane];
    const float rL = P[(1 * BDIM + b) * EDIM + lane];
    const float tL = P[(2 * BDIM + b) * EDIM + lane];
    const float hH = P[(0 * BDIM + b) * EDIM + lane + 64];
    const float rH = P[(1 * BDIM + b) * EDIM + lane + 64];
    const float tH = P[(2 * BDIM + b) * EDIM + lane + 64];
    float vL = s_S[lane] * hL * rL * tL;
    float vH = s_S[lane + 64] * hH * rH * tH;
#pragma unroll
    for (int off = 32; off; off >>= 1) {
      vL += __shfl_down(vL, off, 64);
      vH += __shfl_down(vH, off, 64);
    }
    if (lane == 0) out[b] = -(vL + vH);
  }

  if (t == 0) g_count = 0;  // restore invariant for the next launch / graph replay
}

extern "C" void kernel_launch(void* const* d_in, const int* in_sizes, int n_in,
                              void* d_out, int out_size, void* d_ws, size_t ws_size,
                              hipStream_t stream) {
  const float* head_src = (const float*)d_in[0];
  const float* rel_src  = (const float*)d_in[1];
  const float* tail_src = (const float*)d_in[2];
  const float* W_e      = (const float*)d_in[3];
  const float* b_e      = (const float*)d_in[4];
  const float* W_r      = (const float*)d_in[5];
  const float* b_r      = (const float*)d_in[6];
  const float* core     = (const float*)d_in[7];
  float* out      = (float*)d_out;
  float* partials = (float*)d_ws;          // 1024 floats
  float* P        = (float*)d_ws + 1024;   // 3*64*128 = 24576 floats

  fused_all<<<NBLOCKS, 256, 0, stream>>>(
      core, head_src, rel_src, tail_src, W_e, b_e, W_r, b_r, partials, P, out);
}

// Round 2
// 99.117 us; speedup vs baseline: 1.2728x; 1.2728x over previous
//
#include <hip/hip_runtime.h>

#define HDIM 768
#define EDIM 128
#define BDIM 64

// Grid: 256 core blocks (each reduces 4 of the 8 chunks of one core[i,:,:])
//     + 768 proj blocks. Last block (atomic ticket) does the final combine.
//
// Cross-block visibility WITHOUT agent fences: per-XCD L2s are not coherent,
// and an agent-scope release fence lowers to buffer_wbl2 sc1 (full L2
// writeback). Executed per-block (1024x) that serialized at the TCC and cost
// ~50 us (round-1 measurement). Instead, all cross-block data (partials, P)
// is written with relaxed AGENT-scope atomic stores (global_store ... sc1 =
// write-through to the coherence point) and read back with relaxed
// AGENT-scope loads (bypass stale local caches). Ordering: s_waitcnt
// vmcnt(0) + __syncthreads before a RELAXED agent atomic ticket. No wbl2
// anywhere in the kernel.
#define NCORE_BLOCKS 256
#define NPROJ_BLOCKS 768
#define NBLOCKS (NCORE_BLOCKS + NPROJ_BLOCKS)

#define SC_AGENT __HIP_MEMORY_SCOPE_AGENT

__device__ unsigned int g_count = 0;  // zero at load; last block restores to 0

__global__ __launch_bounds__(256) void fused_all(
    const float* __restrict__ core,
    const float* __restrict__ head_src, const float* __restrict__ rel_src,
    const float* __restrict__ tail_src,
    const float* __restrict__ W_e, const float* __restrict__ b_e,
    const float* __restrict__ W_r, const float* __restrict__ b_r,
    float* __restrict__ partials, float* __restrict__ P,
    float* __restrict__ out) {
  __shared__ float wpart[4][4];   // [chunk u][wave]
  __shared__ float s_S[EDIM];
  __shared__ int s_last;
  const int blk = blockIdx.x;
  const int t = threadIdx.x;
  const int wave = t >> 6, lane = t & 63;

  if (blk < NCORE_BLOCKS) {
    // core[i, :, :] reduction: block handles chunks half*4 .. half*4+3 of i.
    const int i = blk >> 1;
    const int half = blk & 1;
    const float* base = core + (size_t)i * (EDIM * EDIM) + (size_t)half * 8192;
    float s[4];
#pragma unroll
    for (int u = 0; u < 4; ++u) {
      const float4* p = (const float4*)(base + u * 2048);
      const float4 a = p[t];
      const float4 b = p[t + 256];
      s[u] = (a.x + a.y) + (a.z + a.w) + (b.x + b.y) + (b.z + b.w);
    }
#pragma unroll
    for (int off = 32; off; off >>= 1) {
#pragma unroll
      for (int u = 0; u < 4; ++u) s[u] += __shfl_down(s[u], off, 64);
    }
    if (lane == 0) {
#pragma unroll
      for (int u = 0; u < 4; ++u) wpart[u][wave] = s[u];
    }
    __syncthreads();
    if (t < 4) {
      const float v = (wpart[t][0] + wpart[t][1]) + (wpart[t][2] + wpart[t][3]);
      __hip_atomic_store(&partials[i * 8 + half * 4 + t], v,
                         __ATOMIC_RELAXED, SC_AGENT);  // sc1 write-through
    }
  } else {
    // Projections: identical math to the verified kernel.
    const int pid = blk - NCORE_BLOCKS;
    const int wg = pid * 4 + wave;      // 0..3071
    const int ich = wg & 15;            // i-chunk 0..15
    const int mb = wg >> 4;             // 0..191
    const int m = mb >> 6;              // 0=head 1=rel 2=tail
    const int b = mb & 63;

    const float* src  = (m == 0) ? head_src : (m == 1) ? rel_src : tail_src;
    const float* W    = (m == 1) ? W_r : W_e;
    const float* bias = (m == 1) ? b_r : b_e;

    const float4* s4 = (const float4*)(src + b * HDIM);
    const float4 x0 = s4[lane], x1 = s4[lane + 64], x2 = s4[lane + 128];

    const int i0 = ich * 8;
#pragma unroll
    for (int u = 0; u < 8; ++u) {
      const int i = i0 + u;
      const float4* w4 = (const float4*)(W + i * HDIM);
      const float4 w0 = w4[lane], w1 = w4[lane + 64], w2 = w4[lane + 128];
      float d = w0.x * x0.x + w0.y * x0.y + w0.z * x0.z + w0.w * x0.w
              + w1.x * x1.x + w1.y * x1.y + w1.z * x1.z + w1.w * x1.w
              + w2.x * x2.x + w2.y * x2.y + w2.z * x2.z + w2.w * x2.w;
#pragma unroll
      for (int off = 32; off; off >>= 1) d += __shfl_down(d, off, 64);
      if (lane == 0)
        __hip_atomic_store(&P[(m * BDIM + b) * EDIM + i], d + bias[i],
                           __ATOMIC_RELAXED, SC_AGENT);  // sc1 write-through
    }
  }

  // ---- last-block-done rendezvous (no fences, no wbl2) ----
  // sc1 stores complete at the coherence point once vmcnt hits 0.
  asm volatile("s_waitcnt vmcnt(0)" ::: "memory");
  __syncthreads();
  if (t == 0) {
    const unsigned int old =
        __hip_atomic_fetch_add(&g_count, 1u, __ATOMIC_RELAXED, SC_AGENT);
    s_last = (old == (unsigned int)(NBLOCKS - 1));
  }
  __syncthreads();
  if (!s_last) return;

  // Last block: read everything with agent-scope loads (sc1 -> coherence
  // point, never a stale local cache line).
  if (t < EDIM) {
    float S = 0.f;
#pragma unroll
    for (int c = 0; c < 8; ++c)
      S += __hip_atomic_load(&partials[t * 8 + c], __ATOMIC_RELAXED, SC_AGENT);
    s_S[t] = S;
  }
  __syncthreads();

  // Wave w handles b = w*16 .. w*16+15. Lane l covers i=l (low) and i=l+64
  // (high); shuffle trees + (low+high) combine replicate final_kernel exactly.
#pragma unroll 4
  for (int bb = 0; bb < 16; ++bb) {
    const int b = wave * 16 + bb;
    const float hL = __hip_atomic_load(&P[(0 * BDIM + b) * EDIM + lane], __ATOMIC_RELAXED, SC_AGENT);
    const float rL = __hip_atomic_load(&P[(1 * BDIM + b) * EDIM + lane], __ATOMIC_RELAXED, SC_AGENT);
    const float tL = __hip_atomic_load(&P[(2 * BDIM + b) * EDIM + lane], __ATOMIC_RELAXED, SC_AGENT);
    const float hH = __hip_atomic_load(&P[(0 * BDIM + b) * EDIM + lane + 64], __ATOMIC_RELAXED, SC_AGENT);
    const float rH = __hip_atomic_load(&P[(1 * BDIM + b) * EDIM + lane + 64], __ATOMIC_RELAXED, SC_AGENT);
    const float tH = __hip_atomic_load(&P[(2 * BDIM + b) * EDIM + lane + 64], __ATOMIC_RELAXED, SC_AGENT);
    float vL = s_S[lane] * hL * rL * tL;
    float vH = s_S[lane + 64] * hH * rH * tH;
#pragma unroll
    for (int off = 32; off; off >>= 1) {
      vL += __shfl_down(vL, off, 64);
      vH += __shfl_down(vH, off, 64);
    }
    if (lane == 0) out[b] = -(vL + vH);
  }

  if (t == 0)
    __hip_atomic_store(&g_count, 0u, __ATOMIC_RELAXED, SC_AGENT);  // next launch
}

extern "C" void kernel_launch(void* const* d_in, const int* in_sizes, int n_in,
                              void* d_out, int out_size, void* d_ws, size_t ws_size,
                              hipStream_t stream) {
  const float* head_src = (const float*)d_in[0];
  const float* rel_src  = (const float*)d_in[1];
  const float* tail_src = (const float*)d_in[2];
  const float* W_e      = (const float*)d_in[3];
  const float* b_e      = (const float*)d_in[4];
  const float* W_r      = (const float*)d_in[5];
  const float* b_r      = (const float*)d_in[6];
  const float* core     = (const float*)d_in[7];
  float* out      = (float*)d_out;
  float* partials = (float*)d_ws;          // 1024 floats
  float* P        = (float*)d_ws + 1024;   // 3*64*128 = 24576 floats

  fused_all<<<NBLOCKS, 256, 0, stream>>>(
      core, head_src, rel_src, tail_src, W_e, b_e, W_r, b_r, partials, P, out);
}

// Round 3
// 81.240 us; speedup vs baseline: 1.5529x; 1.2200x over previous
//
#include <hip/hip_runtime.h>

#define HDIM 768
#define EDIM 128
#define BDIM 64

// Two-dispatch structure (verified best: round-0 = 80.1 us; single-kernel
// rendezvous variants measured +20..+50 us due to device-scope sync cost on
// non-coherent per-XCD L2s -- rounds 1 & 2).
//
// Dispatch 1 (fused_kernel, 1024 blocks):
//   blocks [0,256):    core[i,:,:] reduction, 4 chunks per block (8 float4
//                      loads in flight per thread -> latency-tolerant).
//   blocks [256,1024): projections, one wave = 8 output channels of (m,b).
// Dispatch 2 (final_kernel, 64 blocks): per-b combine. Plain cached stores
// throughout; cross-dispatch visibility via end-of-kernel flush.
#define NCORE_BLOCKS 256
#define NPROJ_BLOCKS 768

__global__ __launch_bounds__(256) void fused_kernel(
    const float* __restrict__ core,
    const float* __restrict__ head_src, const float* __restrict__ rel_src,
    const float* __restrict__ tail_src,
    const float* __restrict__ W_e, const float* __restrict__ b_e,
    const float* __restrict__ W_r, const float* __restrict__ b_r,
    float* __restrict__ partials, float* __restrict__ P) {
  __shared__ float wpart[4][4];  // [chunk u][wave]
  const int blk = blockIdx.x;
  const int t = threadIdx.x;
  const int wave = t >> 6, lane = t & 63;

  if (blk < NCORE_BLOCKS) {
    // Block handles chunks half*4 .. half*4+3 of core[i,:,:].
    // Per-thread element mapping identical to the verified kernels
    // (chunk base + t, + t+256), so partials are bit-identical.
    const int i = blk >> 1;
    const int half = blk & 1;
    const float* base = core + (size_t)i * (EDIM * EDIM) + (size_t)half * 8192;
    float s[4];
#pragma unroll
    for (int u = 0; u < 4; ++u) {
      const float4* p = (const float4*)(base + u * 2048);
      const float4 a = p[t];
      const float4 b = p[t + 256];
      s[u] = (a.x + a.y) + (a.z + a.w) + (b.x + b.y) + (b.z + b.w);
    }
#pragma unroll
    for (int off = 32; off; off >>= 1) {
#pragma unroll
      for (int u = 0; u < 4; ++u) s[u] += __shfl_down(s[u], off, 64);
    }
    if (lane == 0) {
#pragma unroll
      for (int u = 0; u < 4; ++u) wpart[u][wave] = s[u];
    }
    __syncthreads();
    if (t < 4)
      partials[i * 8 + half * 4 + t] =
          (wpart[t][0] + wpart[t][1]) + (wpart[t][2] + wpart[t][3]);
  } else {
    // Projections: identical math to the verified kernel.
    const int pid = blk - NCORE_BLOCKS;
    const int wg = pid * 4 + wave;  // 0..3071
    const int ich = wg & 15;        // i-chunk 0..15
    const int mb = wg >> 4;         // 0..191
    const int m = mb >> 6;          // 0=head 1=rel 2=tail
    const int b = mb & 63;

    const float* src  = (m == 0) ? head_src : (m == 1) ? rel_src : tail_src;
    const float* W    = (m == 1) ? W_r : W_e;
    const float* bias = (m == 1) ? b_r : b_e;

    const float4* s4 = (const float4*)(src + b * HDIM);
    const float4 x0 = s4[lane], x1 = s4[lane + 64], x2 = s4[lane + 128];

    const int i0 = ich * 8;
#pragma unroll
    for (int u = 0; u < 8; ++u) {
      const int i = i0 + u;
      const float4* w4 = (const float4*)(W + i * HDIM);
      const float4 w0 = w4[lane], w1 = w4[lane + 64], w2 = w4[lane + 128];
      float d = w0.x * x0.x + w0.y * x0.y + w0.z * x0.z + w0.w * x0.w
              + w1.x * x1.x + w1.y * x1.y + w1.z * x1.z + w1.w * x1.w
              + w2.x * x2.x + w2.y * x2.y + w2.z * x2.z + w2.w * x2.w;
#pragma unroll
      for (int off = 32; off; off >>= 1) d += __shfl_down(d, off, 64);
      if (lane == 0) P[(m * BDIM + b) * EDIM + i] = d + bias[i];
    }
  }
}

// Final: one block per b. thread i: val = S[i]*h*r*t; block-reduce -> out[b].
// Byte-identical to the round-0 verified kernel.
__global__ __launch_bounds__(128) void final_kernel(
    const float* __restrict__ partials, const float* __restrict__ P,
    float* __restrict__ out) {
  const int b = blockIdx.x;
  const int i = threadIdx.x;  // 0..127

  float S = 0.f;
#pragma unroll
  for (int c = 0; c < 8; ++c) S += partials[i * 8 + c];

  const float h  = P[(0 * BDIM + b) * EDIM + i];
  const float r  = P[(1 * BDIM + b) * EDIM + i];
  const float tt = P[(2 * BDIM + b) * EDIM + i];
  float val = S * h * r * tt;

  for (int off = 32; off; off >>= 1) val += __shfl_down(val, off, 64);
  __shared__ float wsum[2];
  if ((i & 63) == 0) wsum[i >> 6] = val;
  __syncthreads();
  if (i == 0) out[b] = -(wsum[0] + wsum[1]);
}

extern "C" void kernel_launch(void* const* d_in, const int* in_sizes, int n_in,
                              void* d_out, int out_size, void* d_ws, size_t ws_size,
                              hipStream_t stream) {
  const float* head_src = (const float*)d_in[0];
  const float* rel_src  = (const float*)d_in[1];
  const float* tail_src = (const float*)d_in[2];
  const float* W_e      = (const float*)d_in[3];
  const float* b_e      = (const float*)d_in[4];
  const float* W_r      = (const float*)d_in[5];
  const float* b_r      = (const float*)d_in[6];
  const float* core     = (const float*)d_in[7];
  float* out      = (float*)d_out;
  float* partials = (float*)d_ws;          // 1024 floats
  float* P        = (float*)d_ws + 1024;   // 3*64*128 = 24576 floats

  fused_kernel<<<NCORE_BLOCKS + NPROJ_BLOCKS, 256, 0, stream>>>(
      core, head_src, rel_src, tail_src, W_e, b_e, W_r, b_r, partials, P);
  final_kernel<<<BDIM, 128, 0, stream>>>(partials, P, out);
}